// Round 14
// baseline (1410.534 us; speedup 1.0000x reference)
//
#include <hip/hip_runtime.h>
#include <math.h>

#define S_LEN 400
#define BATCH 32
#define HID   512
#define G3    1536
#define N2    3072
#define VOC   50000
#define OUTW  (VOC + S_LEN)

typedef unsigned long long ull;
typedef unsigned int uint;
typedef unsigned short ushort;
typedef short bf16x8 __attribute__((ext_vector_type(8)));
typedef float f32x4 __attribute__((ext_vector_type(4)));
typedef ushort u16x8 __attribute__((ext_vector_type(8)));

__device__ __forceinline__ float sigf(float x) { return 1.f / (1.f + __expf(-x)); }
__device__ __forceinline__ float tanh_fast(float x) {
  const float xc = fminf(fmaxf(x, -15.f), 15.f);
  const float e = __expf(-2.f * xc);
  return (1.f - e) / (1.f + e);
}
__device__ __forceinline__ ushort f2bf(float f) {       // RNE fp32 -> bf16
  uint u = __float_as_uint(f);
  u += 0x7FFFu + ((u >> 16) & 1u);
  return (ushort)(u >> 16);
}
__device__ __forceinline__ float bf2f(ushort h) {
  return __uint_as_float((uint)h << 16);
}
__device__ __forceinline__ float dot4(float4 a, float4 b) {
  return a.x*b.x + a.y*b.y + a.z*b.z + a.w*b.w;
}

// 64x64 tile transpose helper for the extra blocks embedded in gru_scan.
__device__ void trans_tile_512(const float* __restrict__ srcA,
                               const float* __restrict__ srcB,
                               const int split, const int stride, const int Krows,
                               const int k0, const int n0,
                               ushort* __restrict__ dstH, float* __restrict__ dstF)
{
  __shared__ float tt[64][65];
  const int tid = threadIdx.x;
  const int j = tid & 63, i0 = tid >> 6;    // i0: 0..7
  {
    const int n = n0 + j;
    const float* s = (n < split) ? (srcA + n) : (srcB + (n - split));
    #pragma unroll
    for (int i = i0; i < 64; i += 8)
      tt[i][j] = s[(size_t)(k0 + i) * stride];
  }
  __syncthreads();
  const int ii = tid & 63;
  if (dstH != nullptr) {
    #pragma unroll
    for (int jj = i0; jj < 64; jj += 8)
      dstH[(size_t)(n0 + jj) * Krows + k0 + ii] = f2bf(tt[ii][jj]);
  } else {
    #pragma unroll
    for (int jj = i0; jj < 64; jj += 8)
      dstF[(size_t)(n0 + jj) * Krows + k0 + ii] = tt[ii][jj];
  }
}

// ---------------------------------------------------------------------------
// Persistent bidirectional GRU scan — tagged-packet sync + MFMA matvec.
// Blocks 0..127: the scan (at the measured sync floor ~2.0 us/step).
// Blocks 128..1023: hidden 64x64 weight-transpose tiles on idle CUs.
// enc is emitted in bf16 only (fp32 enc dropped this round).
// ---------------------------------------------------------------------------
__global__ __launch_bounds__(512) void gru_scan(
    const ushort* __restrict__ xzm,           // [32*400][3072] bf16 fw|bw
    const ushort* __restrict__ Utbf,          // [2][1536][512] bf16 (U^T)
    const float* __restrict__ bfw, const float* __restrict__ bbw,
    ushort* __restrict__ enc_bf, ull* __restrict__ hpkt,
    const float* __restrict__ att_Wh, const float* __restrict__ red_W,
    const float* __restrict__ dec_W, const float* __restrict__ dec_U,
    const float* __restrict__ att_Ws, const float* __restrict__ fc_W,
    ushort* __restrict__ Whbf, float* __restrict__ redWt,
    float* __restrict__ decWUt, float* __restrict__ WsT,
    float* __restrict__ fcT)
{
  if (blockIdx.x >= 128) {
    const int tb = blockIdx.x - 128;
    if (tb < 128) {
      trans_tile_512(att_Wh, att_Wh, 512, 512, 1024,
                     (tb % 16) * 64, (tb / 16) * 64, Whbf, nullptr);
    } else if (tb < 256) {
      const int t = tb - 128;
      trans_tile_512(red_W, red_W, 512, 512, 1024,
                     (t % 16) * 64, (t / 16) * 64, nullptr, redWt);
    } else if (tb < 640) {
      const int t = tb - 256;
      trans_tile_512(dec_W, dec_U, G3, G3, 512,
                     (t % 8) * 64, (t / 8) * 64, nullptr, decWUt);
    } else if (tb < 704) {
      const int t = tb - 640;
      trans_tile_512(att_Ws, att_Ws, 512, 512, 512,
                     (t % 8) * 64, (t / 8) * 64, nullptr, WsT);
    } else {
      const int t = tb - 704;
      trans_tile_512(fc_W, fc_W, 512, 512, 1536,
                     (t % 24) * 64, (t / 24) * 64, nullptr, fcT);
    }
    return;
  }

  const int bid = blockIdx.x;        // 0..127
  const int group = bid & 7;
  const int dir = group >> 2;
  const int bg  = group & 3;
  const int ht  = bid >> 3;          // 0..15: j-tile of 32
  const int tid = threadIdx.x;
  const int lane = tid & 63;
  const int w  = tid >> 6;           // wave 0..7
  const int l15 = lane & 15;
  const int lk  = lane >> 4;

  const float* __restrict__ br = (dir ? bbw : bfw) + G3;   // bias row 1

  const int gate = w % 3, jh = w / 3;
  bf16x8 ufrag[16];
  if (w < 6) {
    const ushort* ub = Utbf + ((size_t)dir * G3 + gate * 512 + ht * 32 + jh * 16 + l15) * 512
                     + lk * 8;
    #pragma unroll
    for (int s = 0; s < 16; ++s)
      ufrag[s] = *(const bf16x8*)(ub + s * 32);
  }

  __shared__ ushort h_bf[16][520];       // bf16 h, rows 8-15 zero (16.6 KB)
  __shared__ float redm[3][8][32];       // [gate][batch][j32] (3 KB)

  for (int i = tid; i < 16 * 520; i += 512) ((ushort*)h_bf)[i] = 0;

  const int cb = w;
  const int gbi = tid >> 5;              // 0..7 for tid<256
  const int gj  = tid & 31;
  const int gjq = ht * 32 + gj;
  const int gb  = bg * 8 + (gbi & 7);
  const float brz = br[gjq], brr = br[512 + gjq], brh = br[1024 + gjq];

  ull* __restrict__ pk = hpkt + (size_t)dir * (2 * BATCH * HID);   // [parity][b][j]
  __syncthreads();   // h_bf zero visible

  for (int t = 0; t < S_LEN; ++t) {
    const int ts = dir ? (S_LEN - 1 - t) : t;

    float xzv0 = 0.f, xzv1 = 0.f, xzv2 = 0.f;
    if (tid < 256) {
      const ushort* xp = xzm + ((size_t)gb * S_LEN + ts) * N2 + dir * G3 + gjq;
      xzv0 = bf2f(xp[0]); xzv1 = bf2f(xp[512]); xzv2 = bf2f(xp[1024]);
    }

    // ---- consume h(t): coalesced tagged poll (+ own fp32 hold, tid<256) ----
    float hold = 0.f;
    {
      ull* bp = pk + ((size_t)(t & 1) * BATCH + (bg * 8 + cb)) * HID + lane;
      ull* hp = pk + ((size_t)(t & 1) * BATCH + gb) * HID + gjq;
      const uint tu = (uint)t;
      for (;;) {
        ull v0 = __hip_atomic_load(bp,       __ATOMIC_RELAXED, __HIP_MEMORY_SCOPE_AGENT);
        ull v1 = __hip_atomic_load(bp + 64,  __ATOMIC_RELAXED, __HIP_MEMORY_SCOPE_AGENT);
        ull v2 = __hip_atomic_load(bp + 128, __ATOMIC_RELAXED, __HIP_MEMORY_SCOPE_AGENT);
        ull v3 = __hip_atomic_load(bp + 192, __ATOMIC_RELAXED, __HIP_MEMORY_SCOPE_AGENT);
        ull v4 = __hip_atomic_load(bp + 256, __ATOMIC_RELAXED, __HIP_MEMORY_SCOPE_AGENT);
        ull v5 = __hip_atomic_load(bp + 320, __ATOMIC_RELAXED, __HIP_MEMORY_SCOPE_AGENT);
        ull v6 = __hip_atomic_load(bp + 384, __ATOMIC_RELAXED, __HIP_MEMORY_SCOPE_AGENT);
        ull v7 = __hip_atomic_load(bp + 448, __ATOMIC_RELAXED, __HIP_MEMORY_SCOPE_AGENT);
        bool ok = ((uint)(v0 >> 32) == tu) & ((uint)(v1 >> 32) == tu)
                & ((uint)(v2 >> 32) == tu) & ((uint)(v3 >> 32) == tu)
                & ((uint)(v4 >> 32) == tu) & ((uint)(v5 >> 32) == tu)
                & ((uint)(v6 >> 32) == tu) & ((uint)(v7 >> 32) == tu);
        ull hv = 0;
        if (tid < 256) {
          hv = __hip_atomic_load(hp, __ATOMIC_RELAXED, __HIP_MEMORY_SCOPE_AGENT);
          ok &= ((uint)(hv >> 32) == tu);
        }
        if (__all(ok)) {
          h_bf[cb][lane]       = f2bf(__uint_as_float((uint)v0));
          h_bf[cb][lane + 64]  = f2bf(__uint_as_float((uint)v1));
          h_bf[cb][lane + 128] = f2bf(__uint_as_float((uint)v2));
          h_bf[cb][lane + 192] = f2bf(__uint_as_float((uint)v3));
          h_bf[cb][lane + 256] = f2bf(__uint_as_float((uint)v4));
          h_bf[cb][lane + 320] = f2bf(__uint_as_float((uint)v5));
          h_bf[cb][lane + 384] = f2bf(__uint_as_float((uint)v6));
          h_bf[cb][lane + 448] = f2bf(__uint_as_float((uint)v7));
          if (tid < 256) hold = __uint_as_float((uint)hv);
          break;
        }
        __builtin_amdgcn_s_sleep(1);
      }
    }
    __syncthreads();   // S1: h_bf ready

    if (w < 6) {
      f32x4 acc = f32x4{0.f, 0.f, 0.f, 0.f};
      #pragma unroll
      for (int s = 0; s < 16; ++s) {
        const bf16x8 af = *(const bf16x8*)&h_bf[l15][s * 32 + lk * 8];
        acc = __builtin_amdgcn_mfma_f32_16x16x32_bf16(af, ufrag[s], acc, 0, 0, 0);
      }
      if (lk < 2) {
        #pragma unroll
        for (int r = 0; r < 4; ++r)
          redm[gate][lk * 4 + r][jh * 16 + l15] = acc[r];
      }
    }
    __syncthreads();   // S2: redm ready

    if (tid < 256) {
      const float rz = redm[0][gbi][gj] + brz;
      const float rr = redm[1][gbi][gj] + brr;
      const float rh = redm[2][gbi][gj] + brh;
      const float z  = sigf(xzv0 + rz);
      const float r  = sigf(xzv1 + rr);
      const float hh = tanh_fast(xzv2 + r * rh);
      const float hnew = z * hold + (1.f - z) * hh;
      const ull pack = ((ull)(uint)(t + 1) << 32) | (ull)__float_as_uint(hnew);
      __hip_atomic_store(pk + ((size_t)((t + 1) & 1) * BATCH + gb) * HID + gjq,
                         pack, __ATOMIC_RELAXED, __HIP_MEMORY_SCOPE_AGENT);
      enc_bf[((size_t)gb * S_LEN + ts) * 1024 + dir * 512 + gjq] = f2bf(hnew);
    }
    __syncthreads();   // S3: publishes issued; h_bf/redm safe for next fill
  }
}

// ---------------------------------------------------------------------------
// Merged prep: blocks <3200: embedding gather+convert (Abf);
// blocks 3200..3967: Wt / Utbf transposes (+bias merge).
// ---------------------------------------------------------------------------
__global__ __launch_bounds__(256) void k_prep(
    const int* __restrict__ x_id, const float* __restrict__ emb,
    ushort* __restrict__ Abf,
    const float* __restrict__ fwW, const float* __restrict__ bwW,
    const float* __restrict__ fwb, const float* __restrict__ bwb,
    const float* __restrict__ fwU, const float* __restrict__ bwU,
    ushort* __restrict__ Wt, float* __restrict__ bm,
    ushort* __restrict__ Utbf)
{
  const int tid = threadIdx.x;
  if (blockIdx.x < 3200) {
    const int row = blockIdx.x * 4 + (tid >> 6);
    const int k8 = (tid & 63) * 8;
    const int rid = x_id[row];
    const float4 e0 = *(const float4*)&emb[(size_t)rid * 512 + k8];
    const float4 e1 = *(const float4*)&emb[(size_t)rid * 512 + k8 + 4];
    u16x8 o;
    o[0] = f2bf(e0.x); o[1] = f2bf(e0.y); o[2] = f2bf(e0.z); o[3] = f2bf(e0.w);
    o[4] = f2bf(e1.x); o[5] = f2bf(e1.y); o[6] = f2bf(e1.z); o[7] = f2bf(e1.w);
    *(u16x8*)&Abf[(size_t)row * 512 + k8] = o;
    return;
  }
  __shared__ float tt[64][65];
  const int b = blockIdx.x - 3200;         // 0..767
  const int j = tid & 63, i0 = tid >> 6;   // i0: 0..3
  const float* srcA; const float* srcB; int split, k0, n0; ushort* dst;
  if (b < 384)      { srcA = fwW; srcB = bwW; split = G3;
                      k0 = (b % 8) * 64; n0 = (b / 8) * 64; dst = Wt; }
  else if (b < 576) { const int t = b - 384; srcA = fwU; srcB = fwU; split = N2;
                      k0 = (t % 8) * 64; n0 = (t / 8) * 64; dst = Utbf; }
  else              { const int t = b - 576; srcA = bwU; srcB = bwU; split = N2;
                      k0 = (t % 8) * 64; n0 = (t / 8) * 64;
                      dst = Utbf + (size_t)G3 * 512; }
  {
    const int n = n0 + j;
    const float* s = (n < split) ? (srcA + n) : (srcB + (n - split));
    #pragma unroll
    for (int i = i0; i < 64; i += 4)
      tt[i][j] = s[(size_t)(k0 + i) * G3];
  }
  __syncthreads();
  const int ii = tid & 63;
  #pragma unroll
  for (int jj = i0; jj < 64; jj += 4)
    dst[(size_t)(n0 + jj) * 512 + k0 + ii] = f2bf(tt[ii][jj]);
  if (b < 384 && k0 == 0 && tid < 64) {
    const int n = n0 + tid;
    bm[n] = (n < G3) ? fwb[n] : bwb[n - G3];
  }
}

// ---------------------------------------------------------------------------
// bf16 MFMA GEMM: C[12800][3072] = A @ Wt^T + bm, C bf16.
// 256x128 tile, 4 waves; wave = 64 rows (acc[4][8]); register-prefetch
// staging so next tile's global loads fly under the MFMA block.
// ---------------------------------------------------------------------------
__global__ __launch_bounds__(256) void gemm_bf16(
    const ushort* __restrict__ A,    // [M][512] bf16
    const ushort* __restrict__ Bt,   // [N][512] bf16
    const float* __restrict__ bias,  // [N] fp32
    ushort* __restrict__ C)          // [M][3072] bf16
{
  const int m0 = blockIdx.y * 256, n0 = blockIdx.x * 128;
  const int tid = threadIdx.x;
  const int w = tid >> 6, lane = tid & 63;
  const int l15 = lane & 15, lk = lane >> 4;
  __shared__ short As[256][40];
  __shared__ short Bs[128][40];
  f32x4 acc[4][8];
  #pragma unroll
  for (int i = 0; i < 4; ++i)
    #pragma unroll
    for (int j = 0; j < 8; ++j) acc[i][j] = f32x4{0.f, 0.f, 0.f, 0.f};

  const ushort* arow = A + (size_t)(m0 + tid) * 512;
  const int bsr = tid >> 1, bsc = (tid & 1) * 16;
  const ushort* brow = Bt + (size_t)(n0 + bsr) * 512 + bsc;

  uint4 ga0 = *(const uint4*)(arow + 0);
  uint4 ga1 = *(const uint4*)(arow + 8);
  uint4 ga2 = *(const uint4*)(arow + 16);
  uint4 ga3 = *(const uint4*)(arow + 24);
  uint4 gb0 = *(const uint4*)(brow + 0);
  uint4 gb1 = *(const uint4*)(brow + 8);

  for (int k0 = 0; k0 < 512; k0 += 32) {
    *(uint4*)&As[tid][0]  = ga0;
    *(uint4*)&As[tid][8]  = ga1;
    *(uint4*)&As[tid][16] = ga2;
    *(uint4*)&As[tid][24] = ga3;
    *(uint4*)&Bs[bsr][bsc]     = gb0;
    *(uint4*)&Bs[bsr][bsc + 8] = gb1;
    __syncthreads();
    if (k0 + 32 < 512) {
      ga0 = *(const uint4*)(arow + k0 + 32);
      ga1 = *(const uint4*)(arow + k0 + 40);
      ga2 = *(const uint4*)(arow + k0 + 48);
      ga3 = *(const uint4*)(arow + k0 + 56);
      gb0 = *(const uint4*)(brow + k0 + 32);
      gb1 = *(const uint4*)(brow + k0 + 40);
    }
    bf16x8 af[4], bfr[8];
    #pragma unroll
    for (int rf = 0; rf < 4; ++rf)
      af[rf] = *(const bf16x8*)&As[w * 64 + rf * 16 + l15][lk * 8];
    #pragma unroll
    for (int cf = 0; cf < 8; ++cf)
      bfr[cf] = *(const bf16x8*)&Bs[cf * 16 + l15][lk * 8];
    #pragma unroll
    for (int rf = 0; rf < 4; ++rf)
      #pragma unroll
      for (int cf = 0; cf < 8; ++cf)
        acc[rf][cf] = __builtin_amdgcn_mfma_f32_16x16x32_bf16(
            af[rf], bfr[cf], acc[rf][cf], 0, 0, 0);
    __syncthreads();
  }

  #pragma unroll
  for (int rf = 0; rf < 4; ++rf) {
    #pragma unroll
    for (int cf = 0; cf < 8; ++cf) {
      const int col = n0 + cf * 16 + l15;
      const float bv = bias[col];
      const int rowb = m0 + w * 64 + rf * 16 + lk * 4;
      #pragma unroll
      for (int r = 0; r < 4; ++r)
        C[(size_t)(rowb + r) * N2 + col] = f2bf(acc[rf][cf][r] + bv);
    }
  }
}

// ---------------------------------------------------------------------------
// bf16 MFMA attention-score GEMM, 256x128 tile, register-prefetch staging,
// fused tanh*att_V epilogue with in-wave reduction.
// ---------------------------------------------------------------------------
__global__ __launch_bounds__(256) void gemm_att(
    const ushort* __restrict__ A,    // [12800][1024] bf16
    const ushort* __restrict__ Bt,   // [512][1024] bf16
    const float* __restrict__ dterm, // [32][512] fp32
    const float* __restrict__ attV,  // [512] fp32
    float* __restrict__ e_part)      // [12800][4]
{
  const int m0 = blockIdx.y * 256, n0 = blockIdx.x * 128;
  const int tid = threadIdx.x;
  const int w = tid >> 6, lane = tid & 63;
  const int l15 = lane & 15, lk = lane >> 4;
  __shared__ short As[256][40];
  __shared__ short Bs[128][40];
  f32x4 acc[4][8];
  #pragma unroll
  for (int i = 0; i < 4; ++i)
    #pragma unroll
    for (int j = 0; j < 8; ++j) acc[i][j] = f32x4{0.f, 0.f, 0.f, 0.f};

  const ushort* arow = A + (size_t)(m0 + tid) * 1024;
  const int bsr = tid >> 1, bsc = (tid & 1) * 16;
  const ushort* brow = Bt + (size_t)(n0 + bsr) * 1024 + bsc;

  uint4 ga0 = *(const uint4*)(arow + 0);
  uint4 ga1 = *(const uint4*)(arow + 8);
  uint4 ga2 = *(const uint4*)(arow + 16);
  uint4 ga3 = *(const uint4*)(arow + 24);
  uint4 gb0 = *(const uint4*)(brow + 0);
  uint4 gb1 = *(const uint4*)(brow + 8);

  for (int k0 = 0; k0 < 1024; k0 += 32) {
    *(uint4*)&As[tid][0]  = ga0;
    *(uint4*)&As[tid][8]  = ga1;
    *(uint4*)&As[tid][16] = ga2;
    *(uint4*)&As[tid][24] = ga3;
    *(uint4*)&Bs[bsr][bsc]     = gb0;
    *(uint4*)&Bs[bsr][bsc + 8] = gb1;
    __syncthreads();
    if (k0 + 32 < 1024) {
      ga0 = *(const uint4*)(arow + k0 + 32);
      ga1 = *(const uint4*)(arow + k0 + 40);
      ga2 = *(const uint4*)(arow + k0 + 48);
      ga3 = *(const uint4*)(arow + k0 + 56);
      gb0 = *(const uint4*)(brow + k0 + 32);
      gb1 = *(const uint4*)(brow + k0 + 40);
    }
    bf16x8 af[4], bfr[8];
    #pragma unroll
    for (int rf = 0; rf < 4; ++rf)
      af[rf] = *(const bf16x8*)&As[w * 64 + rf * 16 + l15][lk * 8];
    #pragma unroll
    for (int cf = 0; cf < 8; ++cf)
      bfr[cf] = *(const bf16x8*)&Bs[cf * 16 + l15][lk * 8];
    #pragma unroll
    for (int rf = 0; rf < 4; ++rf)
      #pragma unroll
      for (int cf = 0; cf < 8; ++cf)
        acc[rf][cf] = __builtin_amdgcn_mfma_f32_16x16x32_bf16(
            af[rf], bfr[cf], acc[rf][cf], 0, 0, 0);
    __syncthreads();
  }

  #pragma unroll
  for (int rf = 0; rf < 4; ++rf) {
    #pragma unroll
    for (int r = 0; r < 4; ++r) {
      const int row = m0 + w * 64 + rf * 16 + lk * 4 + r;
      const int b = row / S_LEN;
      float p = 0.f;
      #pragma unroll
      for (int cf = 0; cf < 8; ++cf) {
        const int col = n0 + cf * 16 + l15;
        p += attV[col] * tanh_fast(acc[rf][cf][r] + dterm[(size_t)b * 512 + col]);
      }
      p += __shfl_xor(p, 1); p += __shfl_xor(p, 2);
      p += __shfl_xor(p, 4); p += __shfl_xor(p, 8);
      if (l15 == 0) e_part[(size_t)row * 4 + blockIdx.x] = p;
    }
  }
}

// --------------------------- small kernels ---------------------------------
__global__ __launch_bounds__(128) void k_state(const ushort* __restrict__ encbf,
    const float* __restrict__ redWt, const float* __restrict__ red_b,
    float* __restrict__ state)
{
  const int b = blockIdx.y;
  const int j = blockIdx.x*128 + threadIdx.x;
  __shared__ float hf[512], hb[512];
  const ushort* fw = encbf + ((size_t)b*S_LEN + (S_LEN-1))*1024;
  const ushort* bw = encbf + ((size_t)b*S_LEN)*1024 + 512;
  for (int k = threadIdx.x; k < 512; k += 128) {
    hf[k] = bf2f(fw[k]); hb[k] = bf2f(bw[k]);
  }
  __syncthreads();
  const float4* wr = (const float4*)(redWt + (size_t)j * 1024);
  const float4* hf4 = (const float4*)hf;
  const float4* hb4 = (const float4*)hb;
  float acc = red_b[j];
  #pragma unroll 4
  for (int k = 0; k < 128; ++k) acc += dot4(hf4[k], wr[k]);
  #pragma unroll 4
  for (int k = 0; k < 128; ++k) acc += dot4(hb4[k], wr[128 + k]);
  state[(size_t)b*512 + j] = fmaxf(acc, 0.f);
}

__global__ __launch_bounds__(128) void k_dec(
    const int* __restrict__ y_id, const float* __restrict__ emb,
    const float* __restrict__ state,
    const float* __restrict__ decWUt,
    const float* __restrict__ dec_b, float* __restrict__ dst)
{
  const int b = blockIdx.y;
  const int j = blockIdx.x*128 + threadIdx.x;
  const float4* ye = (const float4*)(emb + (size_t)y_id[b] * 512);
  const float4* st = (const float4*)(state + (size_t)b * 512);
  const float4* w0 = (const float4*)(decWUt + (size_t)(j)        * 512);
  const float4* w1 = (const float4*)(decWUt + (size_t)(512  + j) * 512);
  const float4* w2 = (const float4*)(decWUt + (size_t)(1024 + j) * 512);
  const float4* u0 = (const float4*)(decWUt + (size_t)(G3 + j)        * 512);
  const float4* u1 = (const float4*)(decWUt + (size_t)(G3 + 512  + j) * 512);
  const float4* u2 = (const float4*)(decWUt + (size_t)(G3 + 1024 + j) * 512);
  float xz0 = dec_b[j], xz1 = dec_b[512+j], xz2 = dec_b[1024+j];
  float rc0 = dec_b[G3+j], rc1 = dec_b[G3+512+j], rc2 = dec_b[G3+1024+j];
  #pragma unroll 2
  for (int k = 0; k < 128; ++k) {
    const float4 yv = ye[k], sv = st[k];
    xz0 += dot4(yv, w0[k]); xz1 += dot4(yv, w1[k]); xz2 += dot4(yv, w2[k]);
    rc0 += dot4(sv, u0[k]); rc1 += dot4(sv, u1[k]); rc2 += dot4(sv, u2[k]);
  }
  const float z  = sigf(xz0 + rc0);
  const float r  = sigf(xz1 + rc1);
  const float hh = tanh_fast(xz2 + r*rc2);
  const float sj = state[(size_t)b*512 + j];
  dst[(size_t)b*512 + j] = z*sj + (1.f-z)*hh;
}

__global__ __launch_bounds__(128) void k_dterm(const float* __restrict__ dec,
    const float* __restrict__ WsT, const float* __restrict__ att_bs,
    float* __restrict__ dterm)
{
  const int b = blockIdx.y;
  const int j = blockIdx.x*128 + threadIdx.x;
  const float4* d = (const float4*)(dec + (size_t)b*512);
  const float4* wr = (const float4*)(WsT + (size_t)j * 512);
  float acc = att_bs[j];
  #pragma unroll 4
  for (int k = 0; k < 128; ++k) acc += dot4(d[k], wr[k]);
  dterm[(size_t)b*512 + j] = acc;
}

__global__ __launch_bounds__(512) void k_soft(const float* __restrict__ e_part,
    const int* __restrict__ x_mask, float* __restrict__ wat)
{
  const int b = blockIdx.x, tid = threadIdx.x;
  __shared__ float sm[512];
  float e = -1e30f, ev = 0.f;
  if (tid < S_LEN) {
    const float* ep = e_part + (size_t)(b*S_LEN + tid)*4;
    ev = ep[0]+ep[1]+ep[2]+ep[3] + (float)x_mask[b*S_LEN+tid] * -1e10f;
    e = ev;
  }
  sm[tid] = e; __syncthreads();
  for (int s = 256; s > 0; s >>= 1) { if (tid < s) sm[tid] = fmaxf(sm[tid], sm[tid+s]); __syncthreads(); }
  const float m = sm[0]; __syncthreads();
  const float x = (tid < S_LEN) ? __expf(ev - m) : 0.f;
  sm[tid] = x; __syncthreads();
  for (int s = 256; s > 0; s >>= 1) { if (tid < s) sm[tid] += sm[tid+s]; __syncthreads(); }
  const float inv = 1.f / sm[0];
  if (tid < S_LEN) wat[b*S_LEN+tid] = x * inv;
}

__global__ __launch_bounds__(128) void k_ctx(const float* __restrict__ wat,
    const ushort* __restrict__ encbf, float* __restrict__ ctx)
{
  const int b = blockIdx.y;
  const int j2 = (blockIdx.x*128 + threadIdx.x) * 2;
  float a0 = 0.f, a1 = 0.f;
  const float* w = wat + b*S_LEN;
  const ushort* ep = encbf + (size_t)b*S_LEN*1024 + j2;
  #pragma unroll 4
  for (int s = 0; s < S_LEN; ++s) {
    const uint u = *(const uint*)&ep[(size_t)s*1024];
    a0 += w[s] * bf2f((ushort)u);
    a1 += w[s] * bf2f((ushort)(u >> 16));
  }
  ctx[(size_t)b*1024 + j2]     = a0;
  ctx[(size_t)b*1024 + j2 + 1] = a1;
}

__global__ __launch_bounds__(128) void k_yout(const float* __restrict__ dec,
    const float* __restrict__ ctx, const float* __restrict__ fcT,
    const float* __restrict__ fc_b, float* __restrict__ y_out)
{
  const int b = blockIdx.y;
  const int j = blockIdx.x*128 + threadIdx.x;
  const float4* d = (const float4*)(dec + (size_t)b*512);
  const float4* c = (const float4*)(ctx + (size_t)b*1024);
  const float4* wr = (const float4*)(fcT + (size_t)j * 1536);
  float acc = fc_b[j];
  #pragma unroll 4
  for (int k = 0; k < 128; ++k) acc += dot4(d[k], wr[k]);
  #pragma unroll 4
  for (int k = 0; k < 256; ++k) acc += dot4(c[k], wr[128 + k]);
  y_out[(size_t)b*512 + j] = acc;
}

__global__ __launch_bounds__(256) void k_pgen(const float* __restrict__ ctx,
    const float* __restrict__ dec,
    const int* __restrict__ y_id, const float* __restrict__ emb,
    const float* __restrict__ pg_Wh, const float* __restrict__ pg_Ws,
    const float* __restrict__ pg_Wx, const float* __restrict__ pg_b,
    float* __restrict__ pg)
{
  const int b = blockIdx.x, tid = threadIdx.x;
  __shared__ float sm[256];
  const float* ye = emb + (size_t)y_id[b] * 512;
  float acc = 0.f;
  for (int k = tid; k < 1024; k += 256) acc += ctx[(size_t)b*1024+k]*pg_Wh[k];
  for (int k = tid; k < 512;  k += 256) acc += dec[(size_t)b*512+k]*pg_Ws[k] + ye[k]*pg_Wx[k];
  sm[tid] = acc; __syncthreads();
  for (int s = 128; s > 0; s >>= 1) { if (tid < s) sm[tid] += sm[tid+s]; __syncthreads(); }
  if (tid == 0) pg[b] = sigf(sm[0] + pg_b[0]);
}

// k_vocab: logits + per-(block,b) partial {max, expsum} via wave reduction
__global__ __launch_bounds__(256) void k_vocab(const float* __restrict__ y_out,
    const float* __restrict__ vocab_W, float* __restrict__ logits,
    float* __restrict__ vpart)    // [196][32][2]
{
  __shared__ float y_lds[256][32];
  const int tid = threadIdx.x;
  const int vq = tid & 63, bq = tid >> 6;
  const int v = blockIdx.x * 256 + vq * 4;
  const bool valid = (v < VOC);
  float acc[8][4];
  #pragma unroll
  for (int i = 0; i < 8; ++i)
    #pragma unroll
    for (int j = 0; j < 4; ++j) acc[i][j] = 0.f;
  for (int half = 0; half < 2; ++half) {
    __syncthreads();
    for (int i = 0; i < 32; ++i) {
      const int idx = tid + 256*i;
      const int k = idx >> 5, b = idx & 31;
      y_lds[k][b] = y_out[(size_t)b*512 + half*256 + k];
    }
    __syncthreads();
    if (valid) {
      #pragma unroll 4
      for (int k = 0; k < 256; ++k) {
        const float4 wv = *(const float4*)&vocab_W[(size_t)(half*256 + k) * VOC + v];
        const float4 ya = *(const float4*)&y_lds[k][bq*8];
        const float4 yb = *(const float4*)&y_lds[k][bq*8+4];
        const float yy[8] = {ya.x,ya.y,ya.z,ya.w,yb.x,yb.y,yb.z,yb.w};
        #pragma unroll
        for (int i = 0; i < 8; ++i) {
          acc[i][0] += yy[i]*wv.x; acc[i][1] += yy[i]*wv.y;
          acc[i][2] += yy[i]*wv.z; acc[i][3] += yy[i]*wv.w;
        }
      }
    }
  }
  if (valid) {
    #pragma unroll
    for (int i = 0; i < 8; ++i)
      *(float4*)&logits[(size_t)(bq*8+i)*VOC + v] = make_float4(acc[i][0],acc[i][1],acc[i][2],acc[i][3]);
  }
  // per-wave partial max/expsum for each of this wave's 8 batches
  #pragma unroll
  for (int i = 0; i < 8; ++i) {
    float m = valid ? fmaxf(fmaxf(acc[i][0], acc[i][1]), fmaxf(acc[i][2], acc[i][3]))
                    : -1e30f;
    m = fmaxf(m, __shfl_xor(m, 1));  m = fmaxf(m, __shfl_xor(m, 2));
    m = fmaxf(m, __shfl_xor(m, 4));  m = fmaxf(m, __shfl_xor(m, 8));
    m = fmaxf(m, __shfl_xor(m, 16)); m = fmaxf(m, __shfl_xor(m, 32));
    float s = 0.f;
    if (valid) {
      s = __expf(acc[i][0]-m) + __expf(acc[i][1]-m)
        + __expf(acc[i][2]-m) + __expf(acc[i][3]-m);
    }
    s += __shfl_xor(s, 1);  s += __shfl_xor(s, 2);
    s += __shfl_xor(s, 4);  s += __shfl_xor(s, 8);
    s += __shfl_xor(s, 16); s += __shfl_xor(s, 32);
    if ((tid & 63) == 0) {
      const size_t o = ((size_t)blockIdx.x * 32 + bq * 8 + i) * 2;
      vpart[o] = m; vpart[o + 1] = s;
    }
  }
}

__global__ __launch_bounds__(64) void k_vred2(const float* __restrict__ vpart,
                                              float* __restrict__ red2)
{
  const int b = threadIdx.x;
  if (b >= 32) return;
  float m = -1e30f;
  for (int x = 0; x < 196; ++x) m = fmaxf(m, vpart[((size_t)x*32 + b)*2]);
  float S = 0.f;
  for (int x = 0; x < 196; ++x) {
    const float ml = vpart[((size_t)x*32 + b)*2];
    const float sl = vpart[((size_t)x*32 + b)*2 + 1];
    S += sl * __expf(ml - m);
  }
  red2[b*2] = m; red2[b*2+1] = S;
}

__global__ __launch_bounds__(256) void k_final(const float* __restrict__ logits,
    const float* __restrict__ red2, const float* __restrict__ pg,
    float* __restrict__ out)
{
  const size_t idx = (size_t)blockIdx.x*256 + threadIdx.x;
  const int b = (int)(idx / OUTW);
  const int c = (int)(idx - (size_t)b*OUTW);
  float v = 0.f;
  if (c < VOC) {
    const float m = red2[b*2], s = red2[b*2+1];
    v = pg[b] * __expf(logits[(size_t)b*VOC + c] - m) / s;
  }
  out[idx] = v;
}

__global__ __launch_bounds__(256) void k_scatter(const float* __restrict__ wat,
    const int* __restrict__ x_mask, const float* __restrict__ pg,
    const int* __restrict__ x_id, float* __restrict__ out)
{
  const int i = blockIdx.x*256 + threadIdx.x;   // < 12800
  const int b = i / S_LEN;
  const float aw = wat[i] * (1.f - (float)x_mask[i]) * (1.f - pg[b]);
  atomicAdd(out + (size_t)b*OUTW + x_id[i], aw);
}

// ---------------------------------------------------------------------------
extern "C" void kernel_launch(void* const* d_in, const int* in_sizes, int n_in,
                              void* d_out, int out_size, void* d_ws, size_t ws_size,
                              hipStream_t stream)
{
  (void)in_sizes; (void)n_in; (void)out_size; (void)ws_size;
  const int*   x_id     = (const int*)d_in[0];
  const int*   y_id     = (const int*)d_in[1];
  const int*   x_mask   = (const int*)d_in[2];
  const float* emb      = (const float*)d_in[3];
  const float* enc_fw_W = (const float*)d_in[4];
  const float* enc_fw_U = (const float*)d_in[5];
  const float* enc_fw_b = (const float*)d_in[6];
  const float* enc_bw_W = (const float*)d_in[7];
  const float* enc_bw_U = (const float*)d_in[8];
  const float* enc_bw_b = (const float*)d_in[9];
  const float* red_W    = (const float*)d_in[10];
  const float* red_b    = (const float*)d_in[11];
  const float* dec_W    = (const float*)d_in[12];
  const float* dec_U    = (const float*)d_in[13];
  const float* dec_b    = (const float*)d_in[14];
  const float* att_Wh   = (const float*)d_in[15];
  const float* att_Ws   = (const float*)d_in[16];
  const float* att_bs   = (const float*)d_in[17];
  const float* att_Wc   = (const float*)d_in[18]; (void)att_Wc; // cover == 0
  const float* att_V    = (const float*)d_in[19];
  const float* fc_W     = (const float*)d_in[20];
  const float* fc_b     = (const float*)d_in[21];
  const float* vocab_W  = (const float*)d_in[22];
  const float* pg_Wh    = (const float*)d_in[23];
  const float* pg_Ws    = (const float*)d_in[24];
  const float* pg_Wx    = (const float*)d_in[25];
  const float* pg_b     = (const float*)d_in[26];
  float* out = (float*)d_out;

  const size_t NPKT = (size_t)2*2*BATCH*HID;            // [dir][parity][b][j]
  char* p = (char*)d_ws;
  ushort* xzm   = (ushort*)p; p += (size_t)BATCH*S_LEN*N2*2;     // 78.6 MB
  ushort* encbf = (ushort*)p; p += (size_t)BATCH*S_LEN*1024*2;   // 26.2 MB
  ull*   hpkt   = (ull*)p;    p += NPKT*8;                       // 1 MB
  ushort* Abf   = (ushort*)p; p += (size_t)BATCH*S_LEN*512*2;    // 13.1 MB
  ushort* Wt    = (ushort*)p; p += (size_t)N2*512*2;             // 3.1 MB
  ushort* Whbf  = (ushort*)p; p += (size_t)512*1024*2;           // 1.0 MB
  ushort* Utbf  = (ushort*)p; p += (size_t)2*G3*512*2;           // 3.1 MB
  float*  redWt = (float*)p;  p += (size_t)512*1024*4;           // 2.1 MB
  float*  decWUt= (float*)p;  p += (size_t)N2*512*4;             // 6.3 MB
  float*  WsT   = (float*)p;  p += (size_t)512*512*4;            // 1.0 MB
  float*  fcT   = (float*)p;  p += (size_t)512*1536*4;           // 3.1 MB
  float*  bm    = (float*)p;  p += (size_t)N2*4;
  float*  fstate = (float*)p; p += (size_t)BATCH*HID*4;
  float*  decs   = (float*)p; p += (size_t)BATCH*HID*4;
  float*  dterm  = (float*)p; p += (size_t)BATCH*HID*4;
  float*  epart  = (float*)p; p += (size_t)BATCH*S_LEN*4*4;
  float*  wat    = (float*)p; p += (size_t)BATCH*S_LEN*4;
  float*  ctx    = (float*)p; p += (size_t)BATCH*1024*4;
  float*  yout   = (float*)p; p += (size_t)BATCH*HID*4;
  float*  pg     = (float*)p; p += (size_t)256*4;
  float*  logits = (float*)p; p += (size_t)BATCH*VOC*4;          // 6.4 MB
  float*  red2   = (float*)p; p += (size_t)64*4;
  float*  vpart  = (float*)p; p += (size_t)196*32*2*4;

  hipMemsetAsync(hpkt, 0, NPKT * sizeof(ull), stream);

  // prep: embedding gather->bf16 + Wt/Utbf transposes (one launch)
  k_prep<<<3200 + 768, 256, 0, stream>>>(x_id, emb, Abf,
                                         enc_fw_W, enc_bw_W, enc_fw_b, enc_bw_b,
                                         enc_fw_U, enc_bw_U, Wt, bm, Utbf);
  // merged input projection (bf16 MFMA, 256x128 tiles, reg-prefetch)
  gemm_bf16<<<dim3(N2/128, BATCH*S_LEN/256), 256, 0, stream>>>(Abf, Wt, bm, xzm);
  // persistent GRU scan; blocks 128.. run hidden weight transposes
  gru_scan<<<128 + 896, 512, 0, stream>>>(xzm, Utbf, enc_fw_b, enc_bw_b,
                                          encbf, hpkt,
                                          att_Wh, red_W, dec_W, dec_U, att_Ws,
                                          fc_W, Whbf, redWt, decWUt, WsT, fcT);
  // reduce state + decoder step + attention query term
  k_state<<<dim3(4,32),128,0,stream>>>(encbf, redWt, red_b, fstate);
  k_dec<<<dim3(4,32),128,0,stream>>>(y_id, emb, fstate, decWUt, dec_b, decs);
  k_dterm<<<dim3(4,32),128,0,stream>>>(decs, WsT, att_bs, dterm);
  // attention scores (bf16 MFMA, 256x128 tiles + fused epilogue)
  gemm_att<<<dim3(4, BATCH*S_LEN/256), 256, 0, stream>>>(encbf, Whbf, dterm,
                                                         att_V, epart);
  k_soft<<<32,512,0,stream>>>(epart, x_mask, wat);
  k_ctx<<<dim3(4,32),128,0,stream>>>(wat, encbf, ctx);
  k_yout<<<dim3(4,32),128,0,stream>>>(decs, ctx, fcT, fc_b, yout);
  k_pgen<<<32,256,0,stream>>>(ctx, decs, y_id, emb, pg_Wh, pg_Ws, pg_Wx, pg_b, pg);
  // vocab distribution + final assembly
  k_vocab<<<196,256,0,stream>>>(yout, vocab_W, logits, vpart);
  k_vred2<<<1,64,0,stream>>>(vpart, red2);
  k_final<<<6300,256,0,stream>>>(logits, red2, pg, out);
  k_scatter<<<50,256,0,stream>>>(wat, x_mask, pg, x_id, out);
}

// Round 15
// 1332.522 us; speedup vs baseline: 1.0585x; 1.0585x over previous
//
#include <hip/hip_runtime.h>
#include <math.h>

#define S_LEN 400
#define BATCH 32
#define HID   512
#define G3    1536
#define N2    3072
#define VOC   50000
#define OUTW  (VOC + S_LEN)

typedef unsigned long long ull;
typedef unsigned int uint;
typedef unsigned short ushort;
typedef short bf16x8 __attribute__((ext_vector_type(8)));
typedef float f32x4 __attribute__((ext_vector_type(4)));
typedef ushort u16x8 __attribute__((ext_vector_type(8)));

__device__ __forceinline__ float sigf(float x) { return 1.f / (1.f + __expf(-x)); }
__device__ __forceinline__ float tanh_fast(float x) {
  const float xc = fminf(fmaxf(x, -15.f), 15.f);
  const float e = __expf(-2.f * xc);
  return (1.f - e) / (1.f + e);
}
__device__ __forceinline__ ushort f2bf(float f) {       // RNE fp32 -> bf16
  uint u = __float_as_uint(f);
  u += 0x7FFFu + ((u >> 16) & 1u);
  return (ushort)(u >> 16);
}
__device__ __forceinline__ float bf2f(ushort h) {
  return __uint_as_float((uint)h << 16);
}
__device__ __forceinline__ float dot4(float4 a, float4 b) {
  return a.x*b.x + a.y*b.y + a.z*b.z + a.w*b.w;
}

// 64x64 tile transpose helper for the extra blocks embedded in gru_scan.
__device__ void trans_tile_512(const float* __restrict__ srcA,
                               const float* __restrict__ srcB,
                               const int split, const int stride, const int Krows,
                               const int k0, const int n0,
                               ushort* __restrict__ dstH, float* __restrict__ dstF)
{
  __shared__ float tt[64][65];
  const int tid = threadIdx.x;
  const int j = tid & 63, i0 = tid >> 6;    // i0: 0..7
  {
    const int n = n0 + j;
    const float* s = (n < split) ? (srcA + n) : (srcB + (n - split));
    #pragma unroll
    for (int i = i0; i < 64; i += 8)
      tt[i][j] = s[(size_t)(k0 + i) * stride];
  }
  __syncthreads();
  const int ii = tid & 63;
  if (dstH != nullptr) {
    #pragma unroll
    for (int jj = i0; jj < 64; jj += 8)
      dstH[(size_t)(n0 + jj) * Krows + k0 + ii] = f2bf(tt[ii][jj]);
  } else {
    #pragma unroll
    for (int jj = i0; jj < 64; jj += 8)
      dstF[(size_t)(n0 + jj) * Krows + k0 + ii] = tt[ii][jj];
  }
}

// ---------------------------------------------------------------------------
// Persistent bidirectional GRU scan — tagged-packet sync + MFMA matvec.
// Blocks 0..127: the scan (at the measured sync floor ~2.0 us/step).
// Blocks 128..1023: hidden 64x64 weight-transpose tiles on idle CUs.
// (round-13 structure: emits BOTH fp32 enc and bf16 enc)
// ---------------------------------------------------------------------------
__global__ __launch_bounds__(512) void gru_scan(
    const ushort* __restrict__ xzm,           // [32*400][3072] bf16 fw|bw
    const ushort* __restrict__ Utbf,          // [2][1536][512] bf16 (U^T)
    const float* __restrict__ bfw, const float* __restrict__ bbw,
    float* __restrict__ enc_seq, ushort* __restrict__ enc_bf,
    ull* __restrict__ hpkt,
    const float* __restrict__ att_Wh, const float* __restrict__ red_W,
    const float* __restrict__ dec_W, const float* __restrict__ dec_U,
    const float* __restrict__ att_Ws, const float* __restrict__ fc_W,
    ushort* __restrict__ Whbf, float* __restrict__ redWt,
    float* __restrict__ decWUt, float* __restrict__ WsT,
    float* __restrict__ fcT)
{
  if (blockIdx.x >= 128) {
    const int tb = blockIdx.x - 128;
    if (tb < 128) {
      trans_tile_512(att_Wh, att_Wh, 512, 512, 1024,
                     (tb % 16) * 64, (tb / 16) * 64, Whbf, nullptr);
    } else if (tb < 256) {
      const int t = tb - 128;
      trans_tile_512(red_W, red_W, 512, 512, 1024,
                     (t % 16) * 64, (t / 16) * 64, nullptr, redWt);
    } else if (tb < 640) {
      const int t = tb - 256;
      trans_tile_512(dec_W, dec_U, G3, G3, 512,
                     (t % 8) * 64, (t / 8) * 64, nullptr, decWUt);
    } else if (tb < 704) {
      const int t = tb - 640;
      trans_tile_512(att_Ws, att_Ws, 512, 512, 512,
                     (t % 8) * 64, (t / 8) * 64, nullptr, WsT);
    } else {
      const int t = tb - 704;
      trans_tile_512(fc_W, fc_W, 512, 512, 1536,
                     (t % 24) * 64, (t / 24) * 64, nullptr, fcT);
    }
    return;
  }

  const int bid = blockIdx.x;        // 0..127
  const int group = bid & 7;
  const int dir = group >> 2;
  const int bg  = group & 3;
  const int ht  = bid >> 3;          // 0..15: j-tile of 32
  const int tid = threadIdx.x;
  const int lane = tid & 63;
  const int w  = tid >> 6;           // wave 0..7
  const int l15 = lane & 15;
  const int lk  = lane >> 4;

  const float* __restrict__ br = (dir ? bbw : bfw) + G3;   // bias row 1

  const int gate = w % 3, jh = w / 3;
  bf16x8 ufrag[16];
  if (w < 6) {
    const ushort* ub = Utbf + ((size_t)dir * G3 + gate * 512 + ht * 32 + jh * 16 + l15) * 512
                     + lk * 8;
    #pragma unroll
    for (int s = 0; s < 16; ++s)
      ufrag[s] = *(const bf16x8*)(ub + s * 32);
  }

  __shared__ ushort h_bf[16][520];       // bf16 h, rows 8-15 zero (16.6 KB)
  __shared__ float redm[3][8][32];       // [gate][batch][j32] (3 KB)

  for (int i = tid; i < 16 * 520; i += 512) ((ushort*)h_bf)[i] = 0;

  const int cb = w;
  const int gbi = tid >> 5;              // 0..7 for tid<256
  const int gj  = tid & 31;
  const int gjq = ht * 32 + gj;
  const int gb  = bg * 8 + (gbi & 7);
  const float brz = br[gjq], brr = br[512 + gjq], brh = br[1024 + gjq];

  ull* __restrict__ pk = hpkt + (size_t)dir * (2 * BATCH * HID);   // [parity][b][j]
  __syncthreads();   // h_bf zero visible

  for (int t = 0; t < S_LEN; ++t) {
    const int ts = dir ? (S_LEN - 1 - t) : t;

    float xzv0 = 0.f, xzv1 = 0.f, xzv2 = 0.f;
    if (tid < 256) {
      const ushort* xp = xzm + ((size_t)gb * S_LEN + ts) * N2 + dir * G3 + gjq;
      xzv0 = bf2f(xp[0]); xzv1 = bf2f(xp[512]); xzv2 = bf2f(xp[1024]);
    }

    // ---- consume h(t): coalesced tagged poll (+ own fp32 hold, tid<256) ----
    float hold = 0.f;
    {
      ull* bp = pk + ((size_t)(t & 1) * BATCH + (bg * 8 + cb)) * HID + lane;
      ull* hp = pk + ((size_t)(t & 1) * BATCH + gb) * HID + gjq;
      const uint tu = (uint)t;
      for (;;) {
        ull v0 = __hip_atomic_load(bp,       __ATOMIC_RELAXED, __HIP_MEMORY_SCOPE_AGENT);
        ull v1 = __hip_atomic_load(bp + 64,  __ATOMIC_RELAXED, __HIP_MEMORY_SCOPE_AGENT);
        ull v2 = __hip_atomic_load(bp + 128, __ATOMIC_RELAXED, __HIP_MEMORY_SCOPE_AGENT);
        ull v3 = __hip_atomic_load(bp + 192, __ATOMIC_RELAXED, __HIP_MEMORY_SCOPE_AGENT);
        ull v4 = __hip_atomic_load(bp + 256, __ATOMIC_RELAXED, __HIP_MEMORY_SCOPE_AGENT);
        ull v5 = __hip_atomic_load(bp + 320, __ATOMIC_RELAXED, __HIP_MEMORY_SCOPE_AGENT);
        ull v6 = __hip_atomic_load(bp + 384, __ATOMIC_RELAXED, __HIP_MEMORY_SCOPE_AGENT);
        ull v7 = __hip_atomic_load(bp + 448, __ATOMIC_RELAXED, __HIP_MEMORY_SCOPE_AGENT);
        bool ok = ((uint)(v0 >> 32) == tu) & ((uint)(v1 >> 32) == tu)
                & ((uint)(v2 >> 32) == tu) & ((uint)(v3 >> 32) == tu)
                & ((uint)(v4 >> 32) == tu) & ((uint)(v5 >> 32) == tu)
                & ((uint)(v6 >> 32) == tu) & ((uint)(v7 >> 32) == tu);
        ull hv = 0;
        if (tid < 256) {
          hv = __hip_atomic_load(hp, __ATOMIC_RELAXED, __HIP_MEMORY_SCOPE_AGENT);
          ok &= ((uint)(hv >> 32) == tu);
        }
        if (__all(ok)) {
          h_bf[cb][lane]       = f2bf(__uint_as_float((uint)v0));
          h_bf[cb][lane + 64]  = f2bf(__uint_as_float((uint)v1));
          h_bf[cb][lane + 128] = f2bf(__uint_as_float((uint)v2));
          h_bf[cb][lane + 192] = f2bf(__uint_as_float((uint)v3));
          h_bf[cb][lane + 256] = f2bf(__uint_as_float((uint)v4));
          h_bf[cb][lane + 320] = f2bf(__uint_as_float((uint)v5));
          h_bf[cb][lane + 384] = f2bf(__uint_as_float((uint)v6));
          h_bf[cb][lane + 448] = f2bf(__uint_as_float((uint)v7));
          if (tid < 256) hold = __uint_as_float((uint)hv);
          break;
        }
        __builtin_amdgcn_s_sleep(1);
      }
    }
    __syncthreads();   // S1: h_bf ready

    if (w < 6) {
      f32x4 acc = f32x4{0.f, 0.f, 0.f, 0.f};
      #pragma unroll
      for (int s = 0; s < 16; ++s) {
        const bf16x8 af = *(const bf16x8*)&h_bf[l15][s * 32 + lk * 8];
        acc = __builtin_amdgcn_mfma_f32_16x16x32_bf16(af, ufrag[s], acc, 0, 0, 0);
      }
      if (lk < 2) {
        #pragma unroll
        for (int r = 0; r < 4; ++r)
          redm[gate][lk * 4 + r][jh * 16 + l15] = acc[r];
      }
    }
    __syncthreads();   // S2: redm ready

    if (tid < 256) {
      const float rz = redm[0][gbi][gj] + brz;
      const float rr = redm[1][gbi][gj] + brr;
      const float rh = redm[2][gbi][gj] + brh;
      const float z  = sigf(xzv0 + rz);
      const float r  = sigf(xzv1 + rr);
      const float hh = tanh_fast(xzv2 + r * rh);
      const float hnew = z * hold + (1.f - z) * hh;
      const ull pack = ((ull)(uint)(t + 1) << 32) | (ull)__float_as_uint(hnew);
      __hip_atomic_store(pk + ((size_t)((t + 1) & 1) * BATCH + gb) * HID + gjq,
                         pack, __ATOMIC_RELAXED, __HIP_MEMORY_SCOPE_AGENT);
      const size_t eidx = ((size_t)gb * S_LEN + ts) * 1024 + dir * 512 + gjq;
      enc_seq[eidx] = hnew;
      enc_bf[eidx]  = f2bf(hnew);
    }
    __syncthreads();   // S3: publishes issued; h_bf/redm safe for next fill
  }
}

// ---------------------------------------------------------------------------
// Merged prep: blocks <3200: embedding gather+convert (Abf);
// blocks 3200..3967: Wt / Utbf transposes (+bias merge).
// ---------------------------------------------------------------------------
__global__ __launch_bounds__(256) void k_prep(
    const int* __restrict__ x_id, const float* __restrict__ emb,
    ushort* __restrict__ Abf,
    const float* __restrict__ fwW, const float* __restrict__ bwW,
    const float* __restrict__ fwb, const float* __restrict__ bwb,
    const float* __restrict__ fwU, const float* __restrict__ bwU,
    ushort* __restrict__ Wt, float* __restrict__ bm,
    ushort* __restrict__ Utbf)
{
  const int tid = threadIdx.x;
  if (blockIdx.x < 3200) {
    const int row = blockIdx.x * 4 + (tid >> 6);
    const int k8 = (tid & 63) * 8;
    const int rid = x_id[row];
    const float4 e0 = *(const float4*)&emb[(size_t)rid * 512 + k8];
    const float4 e1 = *(const float4*)&emb[(size_t)rid * 512 + k8 + 4];
    u16x8 o;
    o[0] = f2bf(e0.x); o[1] = f2bf(e0.y); o[2] = f2bf(e0.z); o[3] = f2bf(e0.w);
    o[4] = f2bf(e1.x); o[5] = f2bf(e1.y); o[6] = f2bf(e1.z); o[7] = f2bf(e1.w);
    *(u16x8*)&Abf[(size_t)row * 512 + k8] = o;
    return;
  }
  __shared__ float tt[64][65];
  const int b = blockIdx.x - 3200;         // 0..767
  const int j = tid & 63, i0 = tid >> 6;   // i0: 0..3
  const float* srcA; const float* srcB; int split, k0, n0; ushort* dst;
  if (b < 384)      { srcA = fwW; srcB = bwW; split = G3;
                      k0 = (b % 8) * 64; n0 = (b / 8) * 64; dst = Wt; }
  else if (b < 576) { const int t = b - 384; srcA = fwU; srcB = fwU; split = N2;
                      k0 = (t % 8) * 64; n0 = (t / 8) * 64; dst = Utbf; }
  else              { const int t = b - 576; srcA = bwU; srcB = bwU; split = N2;
                      k0 = (t % 8) * 64; n0 = (t / 8) * 64;
                      dst = Utbf + (size_t)G3 * 512; }
  {
    const int n = n0 + j;
    const float* s = (n < split) ? (srcA + n) : (srcB + (n - split));
    #pragma unroll
    for (int i = i0; i < 64; i += 4)
      tt[i][j] = s[(size_t)(k0 + i) * G3];
  }
  __syncthreads();
  const int ii = tid & 63;
  #pragma unroll
  for (int jj = i0; jj < 64; jj += 4)
    dst[(size_t)(n0 + jj) * 512 + k0 + ii] = f2bf(tt[ii][jj]);
  if (b < 384 && k0 == 0 && tid < 64) {
    const int n = n0 + tid;
    bm[n] = (n < G3) ? fwb[n] : bwb[n - G3];
  }
}

// ---------------------------------------------------------------------------
// bf16 MFMA GEMM: C[12800][3072] = A @ Wt^T + bm, C bf16.
// 128x128 tile, 256 thr (4 waves), 16x16x32 bf16 MFMA, fp32 accum.
// (round-13 proven shape)
// ---------------------------------------------------------------------------
__global__ __launch_bounds__(256) void gemm_bf16(
    const ushort* __restrict__ A,    // [M][512] bf16
    const ushort* __restrict__ Bt,   // [N][512] bf16
    const float* __restrict__ bias,  // [N] fp32
    ushort* __restrict__ C)          // [M][3072] bf16
{
  const int m0 = blockIdx.y * 128, n0 = blockIdx.x * 128;
  const int tid = threadIdx.x;
  const int w = tid >> 6, lane = tid & 63;
  const int l15 = lane & 15, lk = lane >> 4;
  __shared__ short As[128][40];
  __shared__ short Bs[128][40];
  f32x4 acc[2][8];
  #pragma unroll
  for (int i = 0; i < 2; ++i)
    #pragma unroll
    for (int j = 0; j < 8; ++j) acc[i][j] = f32x4{0.f, 0.f, 0.f, 0.f};

  const int sr = tid >> 1;
  const int sc = (tid & 1) * 8;

  for (int k0 = 0; k0 < 512; k0 += 32) {
    const uint4 a0 = *(const uint4*)&A[(size_t)(m0 + sr) * 512 + k0 + sc];
    const uint4 a1 = *(const uint4*)&A[(size_t)(m0 + sr) * 512 + k0 + 16 + sc];
    const uint4 b0 = *(const uint4*)&Bt[(size_t)(n0 + sr) * 512 + k0 + sc];
    const uint4 b1 = *(const uint4*)&Bt[(size_t)(n0 + sr) * 512 + k0 + 16 + sc];
    *(uint4*)&As[sr][sc]      = a0;
    *(uint4*)&As[sr][16 + sc] = a1;
    *(uint4*)&Bs[sr][sc]      = b0;
    *(uint4*)&Bs[sr][16 + sc] = b1;
    __syncthreads();

    bf16x8 af[2], bfr[8];
    #pragma unroll
    for (int rf = 0; rf < 2; ++rf)
      af[rf] = *(const bf16x8*)&As[w * 32 + rf * 16 + l15][lk * 8];
    #pragma unroll
    for (int cf = 0; cf < 8; ++cf)
      bfr[cf] = *(const bf16x8*)&Bs[cf * 16 + l15][lk * 8];
    #pragma unroll
    for (int rf = 0; rf < 2; ++rf)
      #pragma unroll
      for (int cf = 0; cf < 8; ++cf)
        acc[rf][cf] = __builtin_amdgcn_mfma_f32_16x16x32_bf16(
            af[rf], bfr[cf], acc[rf][cf], 0, 0, 0);
    __syncthreads();
  }

  #pragma unroll
  for (int rf = 0; rf < 2; ++rf) {
    #pragma unroll
    for (int cf = 0; cf < 8; ++cf) {
      const int col = n0 + cf * 16 + l15;
      const float bv = bias[col];
      const int rowb = m0 + w * 32 + rf * 16 + lk * 4;
      #pragma unroll
      for (int r = 0; r < 4; ++r)
        C[(size_t)(rowb + r) * N2 + col] = f2bf(acc[rf][cf][r] + bv);
    }
  }
}

// ---------------------------------------------------------------------------
// bf16 MFMA attention-score GEMM with fused epilogue (round-13 shape).
// ---------------------------------------------------------------------------
__global__ __launch_bounds__(256) void gemm_att(
    const ushort* __restrict__ A,    // [12800][1024] bf16
    const ushort* __restrict__ Bt,   // [512][1024] bf16
    const float* __restrict__ dterm, // [32][512] fp32
    const float* __restrict__ attV,  // [512] fp32
    float* __restrict__ e_part)      // [12800][4]
{
  const int m0 = blockIdx.y * 128, n0 = blockIdx.x * 128;
  const int tid = threadIdx.x;
  const int w = tid >> 6, lane = tid & 63;
  const int l15 = lane & 15, lk = lane >> 4;
  __shared__ short As[128][40];
  __shared__ short Bs[128][40];
  f32x4 acc[2][8];
  #pragma unroll
  for (int i = 0; i < 2; ++i)
    #pragma unroll
    for (int j = 0; j < 8; ++j) acc[i][j] = f32x4{0.f, 0.f, 0.f, 0.f};

  const int sr = tid >> 1;
  const int sc = (tid & 1) * 8;

  for (int k0 = 0; k0 < 1024; k0 += 32) {
    const uint4 a0 = *(const uint4*)&A[(size_t)(m0 + sr) * 1024 + k0 + sc];
    const uint4 a1 = *(const uint4*)&A[(size_t)(m0 + sr) * 1024 + k0 + 16 + sc];
    const uint4 b0 = *(const uint4*)&Bt[(size_t)(n0 + sr) * 1024 + k0 + sc];
    const uint4 b1 = *(const uint4*)&Bt[(size_t)(n0 + sr) * 1024 + k0 + 16 + sc];
    *(uint4*)&As[sr][sc]      = a0;
    *(uint4*)&As[sr][16 + sc] = a1;
    *(uint4*)&Bs[sr][sc]      = b0;
    *(uint4*)&Bs[sr][16 + sc] = b1;
    __syncthreads();

    bf16x8 af[2], bfr[8];
    #pragma unroll
    for (int rf = 0; rf < 2; ++rf)
      af[rf] = *(const bf16x8*)&As[w * 32 + rf * 16 + l15][lk * 8];
    #pragma unroll
    for (int cf = 0; cf < 8; ++cf)
      bfr[cf] = *(const bf16x8*)&Bs[cf * 16 + l15][lk * 8];
    #pragma unroll
    for (int rf = 0; rf < 2; ++rf)
      #pragma unroll
      for (int cf = 0; cf < 8; ++cf)
        acc[rf][cf] = __builtin_amdgcn_mfma_f32_16x16x32_bf16(
            af[rf], bfr[cf], acc[rf][cf], 0, 0, 0);
    __syncthreads();
  }

  #pragma unroll
  for (int rf = 0; rf < 2; ++rf) {
    #pragma unroll
    for (int r = 0; r < 4; ++r) {
      const int row = m0 + w * 32 + rf * 16 + lk * 4 + r;
      const int b = row / S_LEN;
      float p = 0.f;
      #pragma unroll
      for (int cf = 0; cf < 8; ++cf) {
        const int col = n0 + cf * 16 + l15;
        p += attV[col] * tanh_fast(acc[rf][cf][r] + dterm[(size_t)b * 512 + col]);
      }
      p += __shfl_xor(p, 1); p += __shfl_xor(p, 2);
      p += __shfl_xor(p, 4); p += __shfl_xor(p, 8);
      if (l15 == 0) e_part[(size_t)row * 4 + blockIdx.x] = p;
    }
  }
}

// --------------------------- small kernels (round-13 fp32 enc) -------------
__global__ __launch_bounds__(128) void k_state(const float* __restrict__ enc,
    const float* __restrict__ redWt, const float* __restrict__ red_b,
    float* __restrict__ state)
{
  const int b = blockIdx.y;
  const int j = blockIdx.x*128 + threadIdx.x;
  const float4* wr = (const float4*)(redWt + (size_t)j * 1024);
  const float4* fw = (const float4*)(enc + ((size_t)b*S_LEN + (S_LEN-1))*1024);
  const float4* bw = (const float4*)(enc + ((size_t)b*S_LEN)*1024 + 512);
  float acc = red_b[j];
  #pragma unroll 4
  for (int k = 0; k < 128; ++k) acc += dot4(fw[k], wr[k]);
  #pragma unroll 4
  for (int k = 0; k < 128; ++k) acc += dot4(bw[k], wr[128 + k]);
  state[(size_t)b*512 + j] = fmaxf(acc, 0.f);
}

__global__ __launch_bounds__(128) void k_dec(
    const int* __restrict__ y_id, const float* __restrict__ emb,
    const float* __restrict__ state,
    const float* __restrict__ decWUt,
    const float* __restrict__ dec_b, float* __restrict__ dst)
{
  const int b = blockIdx.y;
  const int j = blockIdx.x*128 + threadIdx.x;
  const float4* ye = (const float4*)(emb + (size_t)y_id[b] * 512);
  const float4* st = (const float4*)(state + (size_t)b * 512);
  const float4* w0 = (const float4*)(decWUt + (size_t)(j)        * 512);
  const float4* w1 = (const float4*)(decWUt + (size_t)(512  + j) * 512);
  const float4* w2 = (const float4*)(decWUt + (size_t)(1024 + j) * 512);
  const float4* u0 = (const float4*)(decWUt + (size_t)(G3 + j)        * 512);
  const float4* u1 = (const float4*)(decWUt + (size_t)(G3 + 512  + j) * 512);
  const float4* u2 = (const float4*)(decWUt + (size_t)(G3 + 1024 + j) * 512);
  float xz0 = dec_b[j], xz1 = dec_b[512+j], xz2 = dec_b[1024+j];
  float rc0 = dec_b[G3+j], rc1 = dec_b[G3+512+j], rc2 = dec_b[G3+1024+j];
  #pragma unroll 2
  for (int k = 0; k < 128; ++k) {
    const float4 yv = ye[k], sv = st[k];
    xz0 += dot4(yv, w0[k]); xz1 += dot4(yv, w1[k]); xz2 += dot4(yv, w2[k]);
    rc0 += dot4(sv, u0[k]); rc1 += dot4(sv, u1[k]); rc2 += dot4(sv, u2[k]);
  }
  const float z  = sigf(xz0 + rc0);
  const float r  = sigf(xz1 + rc1);
  const float hh = tanh_fast(xz2 + r*rc2);
  const float sj = state[(size_t)b*512 + j];
  dst[(size_t)b*512 + j] = z*sj + (1.f-z)*hh;
}

__global__ __launch_bounds__(128) void k_dterm(const float* __restrict__ dec,
    const float* __restrict__ WsT, const float* __restrict__ att_bs,
    float* __restrict__ dterm)
{
  const int b = blockIdx.y;
  const int j = blockIdx.x*128 + threadIdx.x;
  const float4* d = (const float4*)(dec + (size_t)b*512);
  const float4* wr = (const float4*)(WsT + (size_t)j * 512);
  float acc = att_bs[j];
  #pragma unroll 4
  for (int k = 0; k < 128; ++k) acc += dot4(d[k], wr[k]);
  dterm[(size_t)b*512 + j] = acc;
}

__global__ __launch_bounds__(512) void k_soft(const float* __restrict__ e_part,
    const int* __restrict__ x_mask, float* __restrict__ wat)
{
  const int b = blockIdx.x, tid = threadIdx.x;
  __shared__ float sm[512];
  float e = -1e30f, ev = 0.f;
  if (tid < S_LEN) {
    const float* ep = e_part + (size_t)(b*S_LEN + tid)*4;
    ev = ep[0]+ep[1]+ep[2]+ep[3] + (float)x_mask[b*S_LEN+tid] * -1e10f;
    e = ev;
  }
  sm[tid] = e; __syncthreads();
  for (int s = 256; s > 0; s >>= 1) { if (tid < s) sm[tid] = fmaxf(sm[tid], sm[tid+s]); __syncthreads(); }
  const float m = sm[0]; __syncthreads();
  const float x = (tid < S_LEN) ? __expf(ev - m) : 0.f;
  sm[tid] = x; __syncthreads();
  for (int s = 256; s > 0; s >>= 1) { if (tid < s) sm[tid] += sm[tid+s]; __syncthreads(); }
  const float inv = 1.f / sm[0];
  if (tid < S_LEN) wat[b*S_LEN+tid] = x * inv;
}

__global__ __launch_bounds__(128) void k_ctx(const float* __restrict__ wat,
    const float* __restrict__ enc, float* __restrict__ ctx)
{
  const int b = blockIdx.y;
  const int j = blockIdx.x*128 + threadIdx.x;
  float acc = 0.f;
  const float* w = wat + b*S_LEN;
  const float* ep = enc + (size_t)b*S_LEN*1024 + j;
  #pragma unroll 4
  for (int s = 0; s < S_LEN; ++s) acc += w[s] * ep[(size_t)s*1024];
  ctx[(size_t)b*1024 + j] = acc;
}

__global__ __launch_bounds__(128) void k_yout(const float* __restrict__ dec,
    const float* __restrict__ ctx, const float* __restrict__ fcT,
    const float* __restrict__ fc_b, float* __restrict__ y_out)
{
  const int b = blockIdx.y;
  const int j = blockIdx.x*128 + threadIdx.x;
  const float4* d = (const float4*)(dec + (size_t)b*512);
  const float4* c = (const float4*)(ctx + (size_t)b*1024);
  const float4* wr = (const float4*)(fcT + (size_t)j * 1536);
  float acc = fc_b[j];
  #pragma unroll 4
  for (int k = 0; k < 128; ++k) acc += dot4(d[k], wr[k]);
  #pragma unroll 4
  for (int k = 0; k < 256; ++k) acc += dot4(c[k], wr[128 + k]);
  y_out[(size_t)b*512 + j] = acc;
}

__global__ __launch_bounds__(256) void k_pgen(const float* __restrict__ ctx,
    const float* __restrict__ dec,
    const int* __restrict__ y_id, const float* __restrict__ emb,
    const float* __restrict__ pg_Wh, const float* __restrict__ pg_Ws,
    const float* __restrict__ pg_Wx, const float* __restrict__ pg_b,
    float* __restrict__ pg)
{
  const int b = blockIdx.x, tid = threadIdx.x;
  __shared__ float sm[256];
  const float* ye = emb + (size_t)y_id[b] * 512;
  float acc = 0.f;
  for (int k = tid; k < 1024; k += 256) acc += ctx[(size_t)b*1024+k]*pg_Wh[k];
  for (int k = tid; k < 512;  k += 256) acc += dec[(size_t)b*512+k]*pg_Ws[k] + ye[k]*pg_Wx[k];
  sm[tid] = acc; __syncthreads();
  for (int s = 128; s > 0; s >>= 1) { if (tid < s) sm[tid] += sm[tid+s]; __syncthreads(); }
  if (tid == 0) pg[b] = sigf(sm[0] + pg_b[0]);
}

// k_vocab: logits + per-(block,b) partial {max, expsum} via wave reduction
__global__ __launch_bounds__(256) void k_vocab(const float* __restrict__ y_out,
    const float* __restrict__ vocab_W, float* __restrict__ logits,
    float* __restrict__ vpart)    // [196][32][2]
{
  __shared__ float y_lds[256][32];
  const int tid = threadIdx.x;
  const int vq = tid & 63, bq = tid >> 6;
  const int v = blockIdx.x * 256 + vq * 4;
  const bool valid = (v < VOC);
  float acc[8][4];
  #pragma unroll
  for (int i = 0; i < 8; ++i)
    #pragma unroll
    for (int j = 0; j < 4; ++j) acc[i][j] = 0.f;
  for (int half = 0; half < 2; ++half) {
    __syncthreads();
    for (int i = 0; i < 32; ++i) {
      const int idx = tid + 256*i;
      const int k = idx >> 5, b = idx & 31;
      y_lds[k][b] = y_out[(size_t)b*512 + half*256 + k];
    }
    __syncthreads();
    if (valid) {
      #pragma unroll 4
      for (int k = 0; k < 256; ++k) {
        const float4 wv = *(const float4*)&vocab_W[(size_t)(half*256 + k) * VOC + v];
        const float4 ya = *(const float4*)&y_lds[k][bq*8];
        const float4 yb = *(const float4*)&y_lds[k][bq*8+4];
        const float yy[8] = {ya.x,ya.y,ya.z,ya.w,yb.x,yb.y,yb.z,yb.w};
        #pragma unroll
        for (int i = 0; i < 8; ++i) {
          acc[i][0] += yy[i]*wv.x; acc[i][1] += yy[i]*wv.y;
          acc[i][2] += yy[i]*wv.z; acc[i][3] += yy[i]*wv.w;
        }
      }
    }
  }
  if (valid) {
    #pragma unroll
    for (int i = 0; i < 8; ++i)
      *(float4*)&logits[(size_t)(bq*8+i)*VOC + v] = make_float4(acc[i][0],acc[i][1],acc[i][2],acc[i][3]);
  }
  #pragma unroll
  for (int i = 0; i < 8; ++i) {
    float m = valid ? fmaxf(fmaxf(acc[i][0], acc[i][1]), fmaxf(acc[i][2], acc[i][3]))
                    : -1e30f;
    m = fmaxf(m, __shfl_xor(m, 1));  m = fmaxf(m, __shfl_xor(m, 2));
    m = fmaxf(m, __shfl_xor(m, 4));  m = fmaxf(m, __shfl_xor(m, 8));
    m = fmaxf(m, __shfl_xor(m, 16)); m = fmaxf(m, __shfl_xor(m, 32));
    float s = 0.f;
    if (valid) {
      s = __expf(acc[i][0]-m) + __expf(acc[i][1]-m)
        + __expf(acc[i][2]-m) + __expf(acc[i][3]-m);
    }
    s += __shfl_xor(s, 1);  s += __shfl_xor(s, 2);
    s += __shfl_xor(s, 4);  s += __shfl_xor(s, 8);
    s += __shfl_xor(s, 16); s += __shfl_xor(s, 32);
    if ((tid & 63) == 0) {
      const size_t o = ((size_t)blockIdx.x * 32 + bq * 8 + i) * 2;
      vpart[o] = m; vpart[o + 1] = s;
    }
  }
}

__global__ __launch_bounds__(64) void k_vred2(const float* __restrict__ vpart,
                                              float* __restrict__ red2)
{
  const int b = threadIdx.x;
  if (b >= 32) return;
  float m = -1e30f;
  for (int x = 0; x < 196; ++x) m = fmaxf(m, vpart[((size_t)x*32 + b)*2]);
  float S = 0.f;
  for (int x = 0; x < 196; ++x) {
    const float ml = vpart[((size_t)x*32 + b)*2];
    const float sl = vpart[((size_t)x*32 + b)*2 + 1];
    S += sl * __expf(ml - m);
  }
  red2[b*2] = m; red2[b*2+1] = S;
}

__global__ __launch_bounds__(256) void k_final(const float* __restrict__ logits,
    const float* __restrict__ red2, const float* __restrict__ pg,
    float* __restrict__ out)
{
  const size_t idx = (size_t)blockIdx.x*256 + threadIdx.x;
  const int b = (int)(idx / OUTW);
  const int c = (int)(idx - (size_t)b*OUTW);
  float v = 0.f;
  if (c < VOC) {
    const float m = red2[b*2], s = red2[b*2+1];
    v = pg[b] * __expf(logits[(size_t)b*VOC + c] - m) / s;
  }
  out[idx] = v;
}

__global__ __launch_bounds__(256) void k_scatter(const float* __restrict__ wat,
    const int* __restrict__ x_mask, const float* __restrict__ pg,
    const int* __restrict__ x_id, float* __restrict__ out)
{
  const int i = blockIdx.x*256 + threadIdx.x;   // < 12800
  const int b = i / S_LEN;
  const float aw = wat[i] * (1.f - (float)x_mask[i]) * (1.f - pg[b]);
  atomicAdd(out + (size_t)b*OUTW + x_id[i], aw);
}

// ---------------------------------------------------------------------------
extern "C" void kernel_launch(void* const* d_in, const int* in_sizes, int n_in,
                              void* d_out, int out_size, void* d_ws, size_t ws_size,
                              hipStream_t stream)
{
  (void)in_sizes; (void)n_in; (void)out_size; (void)ws_size;
  const int*   x_id     = (const int*)d_in[0];
  const int*   y_id     = (const int*)d_in[1];
  const int*   x_mask   = (const int*)d_in[2];
  const float* emb      = (const float*)d_in[3];
  const float* enc_fw_W = (const float*)d_in[4];
  const float* enc_fw_U = (const float*)d_in[5];
  const float* enc_fw_b = (const float*)d_in[6];
  const float* enc_bw_W = (const float*)d_in[7];
  const float* enc_bw_U = (const float*)d_in[8];
  const float* enc_bw_b = (const float*)d_in[9];
  const float* red_W    = (const float*)d_in[10];
  const float* red_b    = (const float*)d_in[11];
  const float* dec_W    = (const float*)d_in[12];
  const float* dec_U    = (const float*)d_in[13];
  const float* dec_b    = (const float*)d_in[14];
  const float* att_Wh   = (const float*)d_in[15];
  const float* att_Ws   = (const float*)d_in[16];
  const float* att_bs   = (const float*)d_in[17];
  const float* att_Wc   = (const float*)d_in[18]; (void)att_Wc; // cover == 0
  const float* att_V    = (const float*)d_in[19];
  const float* fc_W     = (const float*)d_in[20];
  const float* fc_b     = (const float*)d_in[21];
  const float* vocab_W  = (const float*)d_in[22];
  const float* pg_Wh    = (const float*)d_in[23];
  const float* pg_Ws    = (const float*)d_in[24];
  const float* pg_Wx    = (const float*)d_in[25];
  const float* pg_b     = (const float*)d_in[26];
  float* out = (float*)d_out;

  const size_t NPKT = (size_t)2*2*BATCH*HID;            // [dir][parity][b][j]
  char* p = (char*)d_ws;
  ushort* xzm   = (ushort*)p; p += (size_t)BATCH*S_LEN*N2*2;     // 78.6 MB
  float*  enc   = (float*)p;  p += (size_t)BATCH*S_LEN*1024*4;   // 52.4 MB
  ushort* encbf = (ushort*)p; p += (size_t)BATCH*S_LEN*1024*2;   // 26.2 MB
  ull*   hpkt   = (ull*)p;    p += NPKT*8;                       // 1 MB
  ushort* Abf   = (ushort*)p; p += (size_t)BATCH*S_LEN*512*2;    // 13.1 MB
  ushort* Wt    = (ushort*)p; p += (size_t)N2*512*2;             // 3.1 MB
  ushort* Whbf  = (ushort*)p; p += (size_t)512*1024*2;           // 1.0 MB
  ushort* Utbf  = (ushort*)p; p += (size_t)2*G3*512*2;           // 3.1 MB
  float*  redWt = (float*)p;  p += (size_t)512*1024*4;           // 2.1 MB
  float*  decWUt= (float*)p;  p += (size_t)N2*512*4;             // 6.3 MB
  float*  WsT   = (float*)p;  p += (size_t)512*512*4;            // 1.0 MB
  float*  fcT   = (float*)p;  p += (size_t)512*1536*4;           // 3.1 MB
  float*  bm    = (float*)p;  p += (size_t)N2*4;
  float*  fstate = (float*)p; p += (size_t)BATCH*HID*4;
  float*  decs   = (float*)p; p += (size_t)BATCH*HID*4;
  float*  dterm  = (float*)p; p += (size_t)BATCH*HID*4;
  float*  epart  = (float*)p; p += (size_t)BATCH*S_LEN*4*4;
  float*  wat    = (float*)p; p += (size_t)BATCH*S_LEN*4;
  float*  ctx    = (float*)p; p += (size_t)BATCH*1024*4;
  float*  yout   = (float*)p; p += (size_t)BATCH*HID*4;
  float*  pg     = (float*)p; p += (size_t)256*4;
  float*  logits = (float*)p; p += (size_t)BATCH*VOC*4;          // 6.4 MB
  float*  red2   = (float*)p; p += (size_t)64*4;
  float*  vpart  = (float*)p; p += (size_t)196*32*2*4;

  hipMemsetAsync(hpkt, 0, NPKT * sizeof(ull), stream);

  // prep: embedding gather->bf16 + Wt/Utbf transposes (one launch)
  k_prep<<<3200 + 768, 256, 0, stream>>>(x_id, emb, Abf,
                                         enc_fw_W, enc_bw_W, enc_fw_b, enc_bw_b,
                                         enc_fw_U, enc_bw_U, Wt, bm, Utbf);
  // merged input projection (bf16 MFMA, 128x128 tiles)
  gemm_bf16<<<dim3(N2/128, BATCH*S_LEN/128), 256, 0, stream>>>(Abf, Wt, bm, xzm);
  // persistent GRU scan; blocks 128.. run hidden weight transposes
  gru_scan<<<128 + 896, 512, 0, stream>>>(xzm, Utbf, enc_fw_b, enc_bw_b,
                                          enc, encbf, hpkt,
                                          att_Wh, red_W, dec_W, dec_U, att_Ws,
                                          fc_W, Whbf, redWt, decWUt, WsT, fcT);
  // reduce state + decoder step + attention query term
  k_state<<<dim3(4,32),128,0,stream>>>(enc, redWt, red_b, fstate);
  k_dec<<<dim3(4,32),128,0,stream>>>(y_id, emb, fstate, decWUt, dec_b, decs);
  k_dterm<<<dim3(4,32),128,0,stream>>>(decs, WsT, att_bs, dterm);
  // attention scores (bf16 MFMA + fused tanh * att_V reduction)
  gemm_att<<<dim3(4, BATCH*S_LEN/128), 256, 0, stream>>>(encbf, Whbf, dterm,
                                                         att_V, epart);
  k_soft<<<32,512,0,stream>>>(epart, x_mask, wat);
  k_ctx<<<dim3(8,32),128,0,stream>>>(wat, enc, ctx);
  k_yout<<<dim3(4,32),128,0,stream>>>(decs, ctx, fcT, fc_b, yout);
  k_pgen<<<32,256,0,stream>>>(ctx, decs, y_id, emb, pg_Wh, pg_Ws, pg_Wx, pg_b, pg);
  // vocab distribution + final assembly (fused softmax partials)
  k_vocab<<<196,256,0,stream>>>(yout, vocab_W, logits, vpart);
  k_vred2<<<1,64,0,stream>>>(vpart, red2);
  k_final<<<6300,256,0,stream>>>(logits, red2, pg, out);
  k_scatter<<<50,256,0,stream>>>(wat, x_mask, pg, x_id, out);
}